// Round 1
// baseline (712.868 us; speedup 1.0000x reference)
//
#include <hip/hip_runtime.h>
#include <cstdint>
#include <cstddef>

// Problem constants (harness fixes N=8192, oim=0).
#define KBAND 64   // csum band half-width stored around the diagonal

// ---------------------------------------------------------------------------
// K1: per-row sequential f32 prefix sums (bit-exact vs np.cumsum), storing:
//   diag[r]        = csum[r][r]
//   back[r]        = inputs[r][r-1]
//   blo[r*K + o]   = csum[r][r-1-o]   (o in [0,K-1], cols r-1 .. r-K)
//   bhi[r*K + o]   = csum[r][r+1+o]   (o in [0,K-1], cols r+1 .. r+K)
// 64 rows per block, rows on wave-0 lanes, LDS-tiled (transpose) loads,
// double-buffered so waves 1-3 stream the next tile while wave 0 scans.
// ---------------------------------------------------------------------------
__global__ __launch_bounds__(256) void k1_prefix_band(
    const float* __restrict__ in, int n,
    float* __restrict__ diag, float* __restrict__ back,
    float* __restrict__ blo, float* __restrict__ bhi) {
  __shared__ float tile[2][64][65];
  const int tid = threadIdx.x;
  const int r0  = blockIdx.x * 64;

  int maxcol = r0 + 63 + KBAND;          // cols needed: j <= r+K-1, max row r0+63
  if (maxcol > n) maxcol = n;
  const int ntiles = (maxcol + 63) >> 6;

  // preload tile 0 (all 256 threads, float4 coalesced)
  for (int e4 = tid; e4 < 1024; e4 += 256) {
    const int rr = e4 >> 4, c4 = (e4 & 15) << 2;
    const float4 v = *(const float4*)(in + (size_t)(r0 + rr) * n + c4);
    tile[0][rr][c4 + 0] = v.x; tile[0][rr][c4 + 1] = v.y;
    tile[0][rr][c4 + 2] = v.z; tile[0][rr][c4 + 3] = v.w;
  }
  __syncthreads();

  float s = 0.0f;                        // sequential accumulator (bit-exact)
  const int r = r0 + (tid & 63);

  for (int tt = 0; tt < ntiles; ++tt) {
    const int buf = tt & 1;
    // waves 1-3: load next tile into the other buffer
    if (tt + 1 < ntiles && tid >= 64) {
      const int c0n = (tt + 1) << 6;
      for (int e4 = tid - 64; e4 < 1024; e4 += 192) {
        const int rr = e4 >> 4, c4 = (e4 & 15) << 2;
        const float4 v = *(const float4*)(in + (size_t)(r0 + rr) * n + c0n + c4);
        tile[buf ^ 1][rr][c4 + 0] = v.x; tile[buf ^ 1][rr][c4 + 1] = v.y;
        tile[buf ^ 1][rr][c4 + 2] = v.z; tile[buf ^ 1][rr][c4 + 3] = v.w;
      }
    }
    if (tid < 64) {                      // wave 0: one lane per row
      const int c0 = tt << 6;
      const bool bandtile = (c0 + 64 > r0 - KBAND);  // tile may touch the band
      if (!bandtile) {
        #pragma unroll 8
        for (int jl = 0; jl < 64; ++jl) s += tile[buf][tid][jl];
      } else {
        for (int jl = 0; jl < 64; ++jl) {
          const float v = tile[buf][tid][jl];
          s += v;
          const int p  = c0 + jl + 1;    // s == csum[r][p]
          const int dp = p - r;
          if (dp >= -KBAND && dp <= KBAND) {
            if (dp < 0)       blo[(size_t)r * KBAND + (-dp - 1)] = s;
            else if (dp == 0) { diag[r] = s; back[r] = v; }
            else              bhi[(size_t)r * KBAND + (dp - 1)] = s;
          }
        }
      }
    }
    __syncthreads();
  }
  if (blockIdx.x == 0 && tid == 0) { diag[0] = 0.0f; back[0] = -1.0f; }
}

// ---------------------------------------------------------------------------
// K2: per segment-start S, find next(S) = first failing c, plus swap/bump
// flags. pack = t | swap<<16 | bump<<17 ; t==n means "no trigger".
// ---------------------------------------------------------------------------
__global__ __launch_bounds__(256) void k2_next(
    const float* __restrict__ in, int n,
    const float* __restrict__ diag, const float* __restrict__ back,
    const float* __restrict__ blo, const float* __restrict__ bhi,
    const float* __restrict__ thp, const float* __restrict__ cbtp,
    int* __restrict__ next_pack) {
  const int S = blockIdx.x * blockDim.x + threadIdx.x;
  if (S >= n) return;
  const float th = *thp, cbt = *cbtp;

  int t = -1;
  for (int c = S + 1; c <= n - 1; ++c) {
    float csS;
    if (S == 0) csS = 0.0f;              // csum[c][0] == 0 exactly
    else {
      const int o = c - 1 - S;
      if (o < KBAND) csS = blo[(size_t)c * KBAND + o];
      else {                             // exact sequential fallback (rare)
        const float* row = in + (size_t)c * n;
        float acc = 0.0f;
        for (int j = 0; j < S; ++j) acc += row[j];
        csS = acc;
      }
    }
    const float mean = (diag[c] - csS) / (float)(c - S);
    if (mean < th) { t = c; break; }
  }

  int pack;
  if (t < 0) pack = n;
  else {
    int swp = 0, bmp = 0;
    const int len_cb = t - S;            // appidx - li
    if (len_cb > 1) {
      float a;
      const int o = t - S - 1;
      if (o < KBAND) a = bhi[(size_t)S * KBAND + o];     // csum[S][t]
      else {
        const float* row = in + (size_t)S * n;
        float acc = 0.0f;
        for (int j = 0; j < t; ++j) acc += row[j];
        a = acc;
      }
      const float b = bhi[(size_t)S * KBAND + 0];        // csum[S][S+1]
      const float cb_mean = (a - b) / (float)(len_cb - 1);
      const float cb_back = (S > 0) ? back[S] : -1.0f;
      if (cb_mean < cbt) { if (cb_back < cbt) swp = 1; else bmp = 1; }
    }
    pack = t | (swp << 16) | (bmp << 17);
  }
  next_pack[S] = pack;
}

// ---------------------------------------------------------------------------
// K3: single block. Wyllie pointer-doubling over next[] to extract the
// trigger chain + ranks, prefix-sum swap flags, emit d[] / padding / dn.
// ---------------------------------------------------------------------------
#define NNODE 8193   // nodes 0..8192 (8192 = terminal)

__global__ __launch_bounds__(1024) void k3_chain(
    const int* __restrict__ next_pack, int n, int* __restrict__ dout) {
  __shared__ unsigned short ptr_[NNODE];   // later reused as trig[rank]
  __shared__ unsigned short dist_[NNODE];
  __shared__ unsigned char  flg_[NNODE];   // bit0 swap, bit1 bump
  __shared__ unsigned char  mark_[NNODE];
  __shared__ int wscan[1024];
  const int tid = threadIdx.x;

  for (int S = tid; S <= n; S += 1024) {
    if (S < n) {
      const int pk = next_pack[S];
      ptr_[S]  = (unsigned short)(pk & 0xFFFF);
      flg_[S]  = (unsigned char)((pk >> 16) & 3);
      dist_[S] = 1;
    } else {
      ptr_[S] = (unsigned short)n; dist_[S] = 0; flg_[S] = 0;
    }
    mark_[S] = (S == 0) ? 1 : 0;
  }
  __syncthreads();

  // 13 doubling rounds (2^13 = 8192 >= max path length)
  for (int rnd = 0; rnd < 13; ++rnd) {
    int p[9], dd[9], pp[9], dS[9], mk[9];
    #pragma unroll 9
    for (int it = 0; it < 9; ++it) {
      const int S = tid + it * 1024;
      if (S <= n) {
        const int pi = ptr_[S];
        p[it] = pi; dd[it] = dist_[pi]; pp[it] = ptr_[pi];
        dS[it] = dist_[S]; mk[it] = mark_[S];
      } else { p[it] = 0; dd[it] = 0; pp[it] = 0; dS[it] = 0; mk[it] = 0; }
    }
    __syncthreads();
    #pragma unroll 9
    for (int it = 0; it < 9; ++it) {
      const int S = tid + it * 1024;
      if (S <= n) {
        dist_[S] = (unsigned short)(dS[it] + dd[it]);
        ptr_[S]  = (unsigned short)pp[it];
        if (mk[it]) mark_[p[it]] = 1;    // same-value write races are benign
      }
    }
    __syncthreads();
  }

  const int dist0 = dist_[0];
  const int M = dist0 - 1;               // number of triggers
  __syncthreads();
  // scatter chain nodes by rank into ptr_ (reuse): trig[rank] = S
  for (int S = tid; S <= n; S += 1024)
    if (mark_[S]) ptr_[dist0 - dist_[S]] = (unsigned short)S;
  __syncthreads();

  // prefix-sum swap flags over triggers k = 0..M-1 (8 per thread)
  const int base = tid * 8;
  int lsw[8], lsum = 0;
  #pragma unroll 8
  for (int i = 0; i < 8; ++i) {
    const int k = base + i;
    lsw[i] = (k < M) ? (flg_[ptr_[k]] & 1) : 0;
    lsum += lsw[i];
  }
  wscan[tid] = lsum;
  __syncthreads();
  for (int off = 1; off < 1024; off <<= 1) {
    int v = (tid >= off) ? wscan[tid - off] : 0;
    __syncthreads();
    wscan[tid] += v;
    __syncthreads();
  }
  const int S_total = wscan[1023];
  const int excl    = wscan[tid] - lsum;
  const int dn      = M + S_total + 1;
  const int bump0   = (M > 0) ? ((flg_[ptr_[0]] >> 1) & 1) : 0;

  // emit d entries; slot algebra verified against reference semantics:
  //  - trigger k appends t_k = trig[k+1] at pos_k = k + swaps_before(k)
  //  - swap: d[pos]=prev (1 if k==0 else t_{k-1}+1 (+bump0 iff k==1)),
  //          d[pos+1]=t_k ; bump_{k+1} lands on trigger k's LAST slot;
  //  - bump_0 self-targets slot 0.
  int run = excl;
  #pragma unroll 8
  for (int i = 0; i < 8; ++i) {
    const int k = base + i;
    if (k < M) {
      const int pos = k + run;
      const int tk  = ptr_[k + 1];
      const int fk  = flg_[ptr_[k]];
      const int swap_k    = fk & 1;
      const int bump_next = (k + 1 < M) ? ((flg_[ptr_[k + 1]] >> 1) & 1) : 0;
      if (swap_k) {
        const int prev = (k == 0) ? 1
                       : ((int)ptr_[k] + 1 + ((k == 1) ? bump0 : 0));
        dout[pos]     = prev;
        dout[pos + 1] = tk + bump_next;
      } else {
        dout[pos] = tk + bump_next + ((k == 0) ? ((fk >> 1) & 1) : 0);
      }
      run += swap_k;
    }
  }
  if (tid == 0) {
    dout[M + S_total]  = n;              // final append: d[dn-1] = n
    dout[2 * n + 2]    = dn;             // dn scalar at flat index 16386
  }
  for (int i2 = dn + tid; i2 < 2 * n + 2; i2 += 1024) dout[i2] = -1;
}

// ---------------------------------------------------------------------------
extern "C" void kernel_launch(void* const* d_in, const int* in_sizes, int n_in,
                              void* d_out, int out_size, void* d_ws, size_t ws_size,
                              hipStream_t stream) {
  const float* in  = (const float*)d_in[0];
  const float* thp = (const float*)d_in[1];
  const float* cbt = (const float*)d_in[2];
  // d_in[3] = oim; harness fixes oim=0 (algorithm specialized for it).

  int n = 1;
  while ((long long)n * n < (long long)in_sizes[0]) ++n;   // n = 8192

  // workspace carve (≈4.3 MB total)
  float* blo  = (float*)d_ws;                  // n*KBAND floats
  float* bhi  = blo  + (size_t)n * KBAND;      // n*KBAND floats
  float* diag = bhi  + (size_t)n * KBAND;      // n floats
  float* back = diag + n;                      // n floats
  int*   npk  = (int*)(back + n);              // n ints

  k1_prefix_band<<<n / 64, 256, 0, stream>>>(in, n, diag, back, blo, bhi);
  k2_next<<<n / 256, 256, 0, stream>>>(in, n, diag, back, blo, bhi, thp, cbt, npk);
  k3_chain<<<1, 1024, 0, stream>>>(npk, n, (int*)d_out);
}

// Round 2
// 497.813 us; speedup vs baseline: 1.4320x; 1.4320x over previous
//
#include <hip/hip_runtime.h>
#include <cstdint>
#include <cstddef>

// Problem constants (harness fixes N=8192, oim=0).
#define KBAND 64   // csum band half-width stored around the diagonal
#define TW    128  // K1 tile width (columns per pipeline step)
#define RPAD  132  // LDS row stride in floats: 132*4=528 B, 16B-aligned rows,
                   // 132%32==4 -> b128 reads/writes hit the 8-touch/bank floor

// ---------------------------------------------------------------------------
// K1: per-row sequential f32 prefix sums (bit-exact vs np.cumsum), storing:
//   diag[r]        = csum[r][r]
//   back[r]        = inputs[r][r-1]
//   blo[r*K + o]   = csum[r][r-1-o]   (o in [0,K-1])
//   bhi[r*K + o]   = csum[r][r+1+o]   (o in [0,K-1])
// 64 rows/block on wave-0 lanes; waves 1-3 stage the next 64x128 tile with
// FULLY UNROLLED register-staged loads (all global_load_dwordx4 issued before
// any LDS store -> one HBM latency per tile, not six).
// ---------------------------------------------------------------------------
__global__ __launch_bounds__(256) void k1_prefix_band(
    const float* __restrict__ in, int n,
    float* __restrict__ diag, float* __restrict__ back,
    float* __restrict__ blo, float* __restrict__ bhi) {
  __shared__ float tile[2][64][RPAD];
  const int tid = threadIdx.x;
  const int r0  = blockIdx.x * 64;

  int maxcol = r0 + 127;                 // cols needed: j <= r+63, max row r0+63
  if (maxcol > n) maxcol = n;
  const int ntiles = (maxcol + TW - 1) / TW;   // n%TW==0 -> loads never cross n

  // preload tile 0: 2048 float4s, 8 per thread, unrolled
  {
    float4 v[8];
    #pragma unroll
    for (int k = 0; k < 8; ++k) {
      const int e4 = tid + 256 * k;
      const int rr = e4 >> 5, c4 = (e4 & 31) << 2;
      v[k] = *(const float4*)(in + (size_t)(r0 + rr) * n + c4);
    }
    #pragma unroll
    for (int k = 0; k < 8; ++k) {
      const int e4 = tid + 256 * k;
      const int rr = e4 >> 5, c4 = (e4 & 31) << 2;
      *(float4*)&tile[0][rr][c4] = v[k];
    }
  }
  __syncthreads();

  float s = 0.0f;                        // sequential accumulator (bit-exact)
  const int r = r0 + (tid & 63);

  for (int tt = 0; tt < ntiles; ++tt) {
    const int buf = tt & 1;
    // waves 1-3: stage tile tt+1 into the other buffer (192 loaders)
    if (tid >= 64 && tt + 1 < ntiles) {
      const int l   = tid - 64;
      const int c0n = (tt + 1) * TW;
      const int cnt = (l < 128) ? 11 : 10;   // 128*11 + 64*10 = 2048
      float4 v[11];
      #pragma unroll
      for (int k = 0; k < 11; ++k) {
        if (k < cnt) {
          const int e4 = l + 192 * k;
          const int rr = e4 >> 5, c4 = (e4 & 31) << 2;
          v[k] = *(const float4*)(in + (size_t)(r0 + rr) * n + c0n + c4);
        }
      }
      #pragma unroll
      for (int k = 0; k < 11; ++k) {
        if (k < cnt) {
          const int e4 = l + 192 * k;
          const int rr = e4 >> 5, c4 = (e4 & 31) << 2;
          *(float4*)&tile[buf ^ 1][rr][c4] = v[k];
        }
      }
    }
    // wave 0: one lane per row, sequential left-to-right adds
    if (tid < 64) {
      const int c0 = tt * TW;
      if (c0 + TW + KBAND <= r0) {       // tile fully below every row's band
        #pragma unroll
        for (int j4 = 0; j4 < 32; ++j4) {
          const float4 v = *(const float4*)&tile[buf][tid][j4 << 2];
          s += v.x; s += v.y; s += v.z; s += v.w;
        }
      } else {                           // band tile: conditional stores
        for (int j4 = 0; j4 < 32; ++j4) {
          const float4 v = *(const float4*)&tile[buf][tid][j4 << 2];
          const float e[4] = {v.x, v.y, v.z, v.w};
          #pragma unroll
          for (int q = 0; q < 4; ++q) {
            const int j = c0 + (j4 << 2) + q;
            if (j < n) {
              s += e[q];
              const int p = j + 1, dp = p - r;
              if (dp >= -KBAND && dp <= KBAND) {
                if (dp < 0)       blo[(size_t)r * KBAND + (-dp - 1)] = s;
                else if (dp == 0) { diag[r] = s; back[r] = e[q]; }
                else              bhi[(size_t)r * KBAND + (dp - 1)] = s;
              }
            }
          }
        }
      }
    }
    __syncthreads();
  }
  if (blockIdx.x == 0 && tid == 0) { diag[0] = 0.0f; back[0] = -1.0f; }
}

// ---------------------------------------------------------------------------
// K2: per segment-start S, find next(S) = first failing c, plus swap/bump
// flags. pack = t | swap<<16 | bump<<17 ; t==n means "no trigger".
// ---------------------------------------------------------------------------
__global__ __launch_bounds__(256) void k2_next(
    const float* __restrict__ in, int n,
    const float* __restrict__ diag, const float* __restrict__ back,
    const float* __restrict__ blo, const float* __restrict__ bhi,
    const float* __restrict__ thp, const float* __restrict__ cbtp,
    int* __restrict__ next_pack) {
  const int S = blockIdx.x * blockDim.x + threadIdx.x;
  if (S >= n) return;
  const float th = *thp, cbt = *cbtp;

  int t = -1;
  for (int c = S + 1; c <= n - 1; ++c) {
    float csS;
    if (S == 0) csS = 0.0f;              // csum[c][0] == 0 exactly
    else {
      const int o = c - 1 - S;
      if (o < KBAND) csS = blo[(size_t)c * KBAND + o];
      else {                             // exact sequential fallback (rare)
        const float* row = in + (size_t)c * n;
        float acc = 0.0f;
        for (int j = 0; j < S; ++j) acc += row[j];
        csS = acc;
      }
    }
    const float mean = (diag[c] - csS) / (float)(c - S);
    if (mean < th) { t = c; break; }
  }

  int pack;
  if (t < 0) pack = n;
  else {
    int swp = 0, bmp = 0;
    const int len_cb = t - S;            // appidx - li
    if (len_cb > 1) {
      float a;
      const int o = t - S - 1;
      if (o < KBAND) a = bhi[(size_t)S * KBAND + o];     // csum[S][t]
      else {
        const float* row = in + (size_t)S * n;
        float acc = 0.0f;
        for (int j = 0; j < t; ++j) acc += row[j];
        a = acc;
      }
      const float b = bhi[(size_t)S * KBAND + 0];        // csum[S][S+1]
      const float cb_mean = (a - b) / (float)(len_cb - 1);
      const float cb_back = (S > 0) ? back[S] : -1.0f;
      if (cb_mean < cbt) { if (cb_back < cbt) swp = 1; else bmp = 1; }
    }
    pack = t | (swp << 16) | (bmp << 17);
  }
  next_pack[S] = pack;
}

// ---------------------------------------------------------------------------
// K3: single block. Wyllie pointer-doubling over next[] to extract the
// trigger chain + ranks, prefix-sum swap flags, emit d[] / padding / dn.
// ---------------------------------------------------------------------------
#define NNODE 8193   // nodes 0..8192 (8192 = terminal)

__global__ __launch_bounds__(1024) void k3_chain(
    const int* __restrict__ next_pack, int n, int* __restrict__ dout) {
  __shared__ unsigned short ptr_[NNODE];   // later reused as trig[rank]
  __shared__ unsigned short dist_[NNODE];
  __shared__ unsigned char  flg_[NNODE];   // bit0 swap, bit1 bump
  __shared__ unsigned char  mark_[NNODE];
  __shared__ int wscan[1024];
  const int tid = threadIdx.x;

  for (int S = tid; S <= n; S += 1024) {
    if (S < n) {
      const int pk = next_pack[S];
      ptr_[S]  = (unsigned short)(pk & 0xFFFF);
      flg_[S]  = (unsigned char)((pk >> 16) & 3);
      dist_[S] = 1;
    } else {
      ptr_[S] = (unsigned short)n; dist_[S] = 0; flg_[S] = 0;
    }
    mark_[S] = (S == 0) ? 1 : 0;
  }
  __syncthreads();

  // 13 doubling rounds (2^13 = 8192 >= max path length)
  for (int rnd = 0; rnd < 13; ++rnd) {
    int p[9], dd[9], pp[9], dS[9], mk[9];
    #pragma unroll 9
    for (int it = 0; it < 9; ++it) {
      const int S = tid + it * 1024;
      if (S <= n) {
        const int pi = ptr_[S];
        p[it] = pi; dd[it] = dist_[pi]; pp[it] = ptr_[pi];
        dS[it] = dist_[S]; mk[it] = mark_[S];
      } else { p[it] = 0; dd[it] = 0; pp[it] = 0; dS[it] = 0; mk[it] = 0; }
    }
    __syncthreads();
    #pragma unroll 9
    for (int it = 0; it < 9; ++it) {
      const int S = tid + it * 1024;
      if (S <= n) {
        dist_[S] = (unsigned short)(dS[it] + dd[it]);
        ptr_[S]  = (unsigned short)pp[it];
        if (mk[it]) mark_[p[it]] = 1;    // same-value write races are benign
      }
    }
    __syncthreads();
  }

  const int dist0 = dist_[0];
  const int M = dist0 - 1;               // number of triggers
  __syncthreads();
  // scatter chain nodes by rank into ptr_ (reuse): trig[rank] = S
  for (int S = tid; S <= n; S += 1024)
    if (mark_[S]) ptr_[dist0 - dist_[S]] = (unsigned short)S;
  __syncthreads();

  // prefix-sum swap flags over triggers k = 0..M-1 (8 per thread)
  const int base = tid * 8;
  int lsw[8], lsum = 0;
  #pragma unroll 8
  for (int i = 0; i < 8; ++i) {
    const int k = base + i;
    lsw[i] = (k < M) ? (flg_[ptr_[k]] & 1) : 0;
    lsum += lsw[i];
  }
  wscan[tid] = lsum;
  __syncthreads();
  for (int off = 1; off < 1024; off <<= 1) {
    int v = (tid >= off) ? wscan[tid - off] : 0;
    __syncthreads();
    wscan[tid] += v;
    __syncthreads();
  }
  const int S_total = wscan[1023];
  const int excl    = wscan[tid] - lsum;
  const int dn      = M + S_total + 1;
  const int bump0   = (M > 0) ? ((flg_[ptr_[0]] >> 1) & 1) : 0;

  // emit d entries; slot algebra:
  //  - trigger k appends t_k = trig[k+1] at pos_k = k + swaps_before(k)
  //  - swap: d[pos]=prev (1 if k==0 else t_{k-1}+1 (+bump0 iff k==1)),
  //          d[pos+1]=t_k ; bump_{k+1} lands on trigger k's LAST slot;
  //  - bump_0 self-targets slot 0.
  int run = excl;
  #pragma unroll 8
  for (int i = 0; i < 8; ++i) {
    const int k = base + i;
    if (k < M) {
      const int pos = k + run;
      const int tk  = ptr_[k + 1];
      const int fk  = flg_[ptr_[k]];
      const int swap_k    = fk & 1;
      const int bump_next = (k + 1 < M) ? ((flg_[ptr_[k + 1]] >> 1) & 1) : 0;
      if (swap_k) {
        const int prev = (k == 0) ? 1
                       : ((int)ptr_[k] + 1 + ((k == 1) ? bump0 : 0));
        dout[pos]     = prev;
        dout[pos + 1] = tk + bump_next;
      } else {
        dout[pos] = tk + bump_next + ((k == 0) ? ((fk >> 1) & 1) : 0);
      }
      run += swap_k;
    }
  }
  if (tid == 0) {
    dout[M + S_total]  = n;              // final append: d[dn-1] = n
    dout[2 * n + 2]    = dn;             // dn scalar at flat index 16386
  }
  for (int i2 = dn + tid; i2 < 2 * n + 2; i2 += 1024) dout[i2] = -1;
}

// ---------------------------------------------------------------------------
extern "C" void kernel_launch(void* const* d_in, const int* in_sizes, int n_in,
                              void* d_out, int out_size, void* d_ws, size_t ws_size,
                              hipStream_t stream) {
  const float* in  = (const float*)d_in[0];
  const float* thp = (const float*)d_in[1];
  const float* cbt = (const float*)d_in[2];
  // d_in[3] = oim; harness fixes oim=0 (algorithm specialized for it).

  int n = 1;
  while ((long long)n * n < (long long)in_sizes[0]) ++n;   // n = 8192

  // workspace carve (≈4.3 MB total)
  float* blo  = (float*)d_ws;                  // n*KBAND floats
  float* bhi  = blo  + (size_t)n * KBAND;      // n*KBAND floats
  float* diag = bhi  + (size_t)n * KBAND;      // n floats
  float* back = diag + n;                      // n floats
  int*   npk  = (int*)(back + n);              // n ints

  k1_prefix_band<<<n / 64, 256, 0, stream>>>(in, n, diag, back, blo, bhi);
  k2_next<<<n / 256, 256, 0, stream>>>(in, n, diag, back, blo, bhi, thp, cbt, npk);
  k3_chain<<<1, 1024, 0, stream>>>(npk, n, (int*)d_out);
}